// Round 1
// baseline (104.277 us; speedup 1.0000x reference)
//
#include <hip/hip_runtime.h>

#define NLAYER 255          // layers l = 1..255, layer_id = l-1
#define SEQ    256          // cumsum length
#define TOTJ   32640        // sum_{l=1}^{255} (256-l)
#define CHUNKS 8
#define CHUNK_J (TOTJ / CHUNKS)   // 4080 (multiple of 4)
#define CHUNK_F4 (CHUNK_J / 4)    // 1020
#define THREADS 256

// ---------------------------------------------------------------------------
// Kernel A: build packed (layer_id | lo<<8) table, one block per layer.
// S(l) = 256*(l-1) - (l-1)*l/2 is the flat offset of layer l's segment.
// ---------------------------------------------------------------------------
__global__ void build_table(unsigned short* __restrict__ table) {
    int l = blockIdx.x + 1;            // 1..255
    int n = 256 - l;
    int i = threadIdx.x;
    if (i < n) {
        int base = 256 * (l - 1) - ((l - 1) * l) / 2;
        table[base + i] = (unsigned short)((l - 1) | (i << 8));
    }
}

// ---------------------------------------------------------------------------
// Kernel B: main. grid = (CHUNKS, B). Block handles one (row, j-chunk).
//  - LDS inclusive scan of d row -> c[256] (c[0]=0)
//  - w[l_idx] = mask^2.5 / count_l  in LDS
//  - stream hvec chunk with float4, decode table with ushort4
//  - per-block partial sum -> partials[]
// ---------------------------------------------------------------------------
__global__ __launch_bounds__(THREADS) void main_kernel(
        const float* __restrict__ d1layer,        // B x 255
        const float* __restrict__ hvec,           // B x 32640
        const float* __restrict__ mask,           // B x 255
        const unsigned short* __restrict__ table, // 32640
        float* __restrict__ partials)             // CHUNKS*B
{
    __shared__ float c[SEQ];
    __shared__ float w[NLAYER];
    __shared__ float red[THREADS / 64];

    const int b     = blockIdx.y;
    const int chunk = blockIdx.x;
    const int t     = threadIdx.x;

    // stage d (shifted by 1) and w
    c[t] = (t > 0) ? d1layer[b * NLAYER + (t - 1)] : 0.0f;
    if (t < NLAYER) {
        float mk = mask[b * NLAYER + t];
        // mask^2.5 = mk*mk*sqrt(mk); fold /count_l (count = 255 - layer_id)
        w[t] = mk * mk * sqrtf(mk) / (float)(NLAYER - t);
    }
    __syncthreads();

    // Hillis-Steele inclusive scan over 256 entries -> c[i] = sum d[0..i-1]
    #pragma unroll
    for (int off = 1; off < SEQ; off <<= 1) {
        float v   = c[t];
        float add = (t >= off) ? c[t - off] : 0.0f;
        __syncthreads();
        c[t] = v + add;
        __syncthreads();
    }

    const float4* hv4 =
        (const float4*)(hvec + (size_t)b * TOTJ + (size_t)chunk * CHUNK_J);
    const unsigned short* tb = table + chunk * CHUNK_J;

    float acc = 0.0f;
    for (int f4 = t; f4 < CHUNK_F4; f4 += THREADS) {
        float4 h = hv4[f4];
        ushort4 tv = *(const ushort4*)(tb + f4 * 4);

        int l0 = tv.x & 0xFF, lo0 = tv.x >> 8;
        int l1 = tv.y & 0xFF, lo1 = tv.y >> 8;
        int l2 = tv.z & 0xFF, lo2 = tv.z >> 8;
        int l3 = tv.w & 0xFF, lo3 = tv.w >> 8;

        float d0 = (c[lo0 + l0 + 1] - c[lo0]) - h.x;
        float d1 = (c[lo1 + l1 + 1] - c[lo1]) - h.y;
        float d2 = (c[lo2 + l2 + 1] - c[lo2]) - h.z;
        float d3 = (c[lo3 + l3 + 1] - c[lo3]) - h.w;

        acc += d0 * d0 * w[l0];
        acc += d1 * d1 * w[l1];
        acc += d2 * d2 * w[l2];
        acc += d3 * d3 * w[l3];
    }

    // wave (64-lane) shuffle reduce, then cross-wave via LDS
    #pragma unroll
    for (int off = 32; off > 0; off >>= 1)
        acc += __shfl_down(acc, off, 64);
    int lane = t & 63, wid = t >> 6;
    if (lane == 0) red[wid] = acc;
    __syncthreads();
    if (t == 0) {
        float s = 0.0f;
        #pragma unroll
        for (int i = 0; i < THREADS / 64; ++i) s += red[i];
        partials[b * gridDim.x + chunk] = s;
    }
}

// ---------------------------------------------------------------------------
// Kernel C: reduce partials, scale by 1/(255*B), write scalar.
// ---------------------------------------------------------------------------
__global__ void reduce_kernel(const float* __restrict__ partials, int n, int B,
                              float* __restrict__ out) {
    __shared__ float red[16];
    float acc = 0.0f;
    for (int i = threadIdx.x; i < n; i += blockDim.x) acc += partials[i];
    #pragma unroll
    for (int off = 32; off > 0; off >>= 1)
        acc += __shfl_down(acc, off, 64);
    int lane = threadIdx.x & 63, wid = threadIdx.x >> 6;
    if (lane == 0) red[wid] = acc;
    __syncthreads();
    if (threadIdx.x == 0) {
        float s = 0.0f;
        int nw = blockDim.x >> 6;
        for (int i = 0; i < nw; ++i) s += red[i];
        out[0] = s / ((float)NLAYER * (float)B);
    }
}

// ---------------------------------------------------------------------------
extern "C" void kernel_launch(void* const* d_in, const int* in_sizes, int n_in,
                              void* d_out, int out_size, void* d_ws, size_t ws_size,
                              hipStream_t stream) {
    const float* d1layer = (const float*)d_in[0];   // B x 1 x 255
    const float* hvec    = (const float*)d_in[1];   // B x 32640
    const float* mask    = (const float*)d_in[2];   // B x 255
    float* out = (float*)d_out;

    const int B = in_sizes[2] / NLAYER;             // 512

    // workspace layout: [ table: 32640 ushort = 65280 B ][ partials: CHUNKS*B floats ]
    unsigned short* table = (unsigned short*)d_ws;
    float* partials = (float*)((char*)d_ws + TOTJ * sizeof(unsigned short));

    build_table<<<NLAYER, 256, 0, stream>>>(table);

    dim3 grid(CHUNKS, B);
    main_kernel<<<grid, THREADS, 0, stream>>>(d1layer, hvec, mask, table, partials);

    reduce_kernel<<<1, 1024, 0, stream>>>(partials, CHUNKS * B, B, out);
}